// Round 18
// baseline (425.045 us; speedup 1.0000x reference)
//
#include <hip/hip_runtime.h>
#include <stdint.h>

// net_gcn_multitask — MI355X.
//   memset: bucket cursors = 0
//   D1 bin_conv_prep: [bin | convx | w0t/wcatT]      (pure memory-bound)
//   D2 csr_mask: [per-bucket CSR (49 CUs) | threefry masks (207 CUs, spatial)]
//   D3 spmm_x: t = spmm(xb)       [16x unrolled, cv-prefetch pipeline, nt hints]
//   D4 pass_a: U=relu(t@W0) [MFMA]; z=[drop1(U)@W1 | drop2(U)@Wss], 256B rows
//   D5 gather_out: h|s = spmm(z)  [16x unrolled, cv-prefetch pipeline, nt hints]

#define NN 100000
#define NE 1600000
#define D 128
#define NW 400000
#define ZCP 128        // padded z row stride (ushorts) = 256 B
#define DO1 40
#define DO2 64
#define OUT_S_OFF 4000000
#define KEEP_THR 6710886u
#define NB 49
#define CAP 36000
#define BINB 196
#define CONVB 12500
#define WPREPB 120
#define MASK1K 782     // ceil(2*NW / 1024)

typedef unsigned int uint;
typedef __attribute__((ext_vector_type(4))) float f32x4;
typedef __attribute__((ext_vector_type(8))) short short8;
typedef __attribute__((ext_vector_type(2))) uint u32x2;
union U4S8 { uint4 u; short8 s; };

// nontemporal helpers on native vector types
__device__ __forceinline__ u32x2 ntl_u2(const uint2* p) {
  return __builtin_nontemporal_load((const u32x2*)p);
}
__device__ __forceinline__ void nts_u2(uint2* p, uint lo, uint hi) {
  u32x2 v; v.x = lo; v.y = hi;
  __builtin_nontemporal_store(v, (u32x2*)p);
}
__device__ __forceinline__ void nts_f4(float* p, float a, float b, float c, float d) {
  f32x4 v; v.x = a; v.y = b; v.z = c; v.w = d;
  __builtin_nontemporal_store(v, (f32x4*)p);
}

// ---------------- bf16 helpers ----------------
__device__ __forceinline__ float bflo(uint p) { return __uint_as_float(p << 16); }
__device__ __forceinline__ float bfhi(uint p) { return __uint_as_float(p & 0xffff0000u); }
__device__ __forceinline__ uint f2bf(float f) {
  uint u = __float_as_uint(f);
  return (u + 0x7fffu + ((u >> 16) & 1u)) >> 16;   // RTNE
}
__device__ __forceinline__ uint pack2(float lo, float hi) {
  return f2bf(lo) | (f2bf(hi) << 16);
}

// ------- threefry2x32 (JAX partitionable; verified) ---------------------
#define ROTL(x, r) __builtin_rotateleft32((x), (r))
__device__ __forceinline__ void tf2x32(uint k0, uint k1, uint x0, uint x1,
                                       uint& o0, uint& o1) {
  uint ks2 = k0 ^ k1 ^ 0x1BD11BDAu;
  x0 += k0; x1 += k1;
#define TFR(r) { x0 += x1; x1 = ROTL(x1, r); x1 ^= x0; }
  TFR(13) TFR(15) TFR(26) TFR(6)
  x0 += k1;  x1 += ks2 + 1u;
  TFR(17) TFR(29) TFR(16) TFR(24)
  x0 += ks2; x1 += k0 + 2u;
  TFR(13) TFR(15) TFR(26) TFR(6)
  x0 += k0;  x1 += k1 + 3u;
  TFR(17) TFR(29) TFR(16) TFR(24)
  x0 += k1;  x1 += ks2 + 4u;
  TFR(13) TFR(15) TFR(26) TFR(6)
  x0 += ks2; x1 += k0 + 5u;
#undef TFR
  o0 = x0; o1 = x1;
}

// ---- D1: [bin | convx | weight transpose], 256 thr (pure memory) ---------
__global__ void bin_conv_prep_kernel(
    const int* __restrict__ row, const int* __restrict__ col,
    const float* __restrict__ val, int* __restrict__ cursor,
    uint2* __restrict__ buck,
    const float* __restrict__ x, uint* __restrict__ xb,
    const float* __restrict__ W0, const float* __restrict__ W1,
    const float* __restrict__ Wss,
    ushort* __restrict__ w0t, ushort* __restrict__ wcatT) {
  int bid = blockIdx.x, tid = threadIdx.x;
  if (bid < BINB) {
    __shared__ int h[NB];
    __shared__ int base[NB];
    if (tid < NB) h[tid] = 0;
    __syncthreads();
    int e0 = bid * 8192;
#pragma unroll 4
    for (int j = 0; j < 32; ++j) {
      int e = e0 + j * 256 + tid;
      if (e < NE) atomicAdd(&h[row[e] >> 11], 1);
    }
    __syncthreads();
    if (tid < NB) {
      int c = h[tid];
      base[tid] = c ? (tid * CAP + atomicAdd(&cursor[tid], c)) : 0;
      h[tid] = 0;
    }
    __syncthreads();
#pragma unroll 4
    for (int j = 0; j < 32; ++j) {
      int e = e0 + j * 256 + tid;
      if (e < NE) {
        int r = row[e];
        int b = r >> 11;
        int k = atomicAdd(&h[b], 1);
        int idx = base[b] + k;
        int lim = (b + 1) * CAP;
        if (idx >= lim) idx = lim - 1;   // overflow guard (never at 18 sigma)
        buck[idx] = make_uint2(((uint)(r & 2047) << 17) | (uint)col[e],
                               __float_as_uint(val[e]));
      }
    }
  } else if (bid < BINB + CONVB) {
    int i = (bid - BINB) * 256 + tid;   // float4 index, 3.2M
    f32x4 v = __builtin_nontemporal_load((const f32x4*)x + i);
    nts_u2((uint2*)xb + i, pack2(v.x, v.y), pack2(v.z, v.w));
  } else {
    int idx = (bid - BINB - CONVB) * 256 + tid;   // 0..30719
    if (idx < 16384) {
      int c = idx >> 7, k = idx & 127;
      w0t[idx] = (ushort)f2bf(W0[k * D + c]);
    } else {
      int j = idx - 16384;                         // 0..14335
      int c = j >> 7, k = j & 127;
      float v = (c < 40) ? W1[k * DO1 + c] : ((c < 48) ? 0.f : Wss[k * DO2 + (c - 48)]);
      wcatT[j] = (ushort)f2bf(v);
    }
  }
}

// ---- D2: [csr (49 blocks) | masks (782 blocks, spatial)] 1024 thr --------
__global__ __launch_bounds__(1024) void csr_mask_kernel(
    const uint2* __restrict__ buck, const int* __restrict__ cursor,
    int* __restrict__ ptr, uint2* __restrict__ cv,
    uint* __restrict__ m1, uint* __restrict__ m2) {
  int bid = blockIdx.x, tid = threadIdx.x;
  if (bid >= NB) {
    int t = (bid - NB) * 1024 + tid;
    if (t >= 2 * NW) return;
    uint a0, a1, b0, b1;
    tf2x32(0u, 42u, 0u, 0u, a0, a1);   // child key 0 (const-folded)
    tf2x32(0u, 42u, 0u, 1u, b0, b1);   // child key 1
    bool second = (t >= NW);
    uint w  = second ? (uint)(t - NW) : (uint)t;
    uint k0 = second ? b0 : a0;
    uint k1 = second ? b1 : a1;
    uint base = w * 32u;
    uint word = 0u;
#pragma unroll
    for (int i = 0; i < 32; ++i) {
      uint o0, o1;
      tf2x32(k0, k1, 0u, base + (uint)i, o0, o1);
      word |= (uint)(((o0 ^ o1) >> 9) <= KEEP_THR) << i;
    }
    (second ? m2 : m1)[w] = word;
    return;
  }
  __shared__ int cnt[2048];
  __shared__ int sc[2048];
  __shared__ int cb[NB];
  int b = bid;
  if (tid < NB) cb[tid] = min(cursor[tid], CAP);
  int i0 = tid, i1 = tid + 1024;
  cnt[i0] = 0; cnt[i1] = 0;
  __syncthreads();
  int gbase = 0;
  for (int i = 0; i < b; ++i) gbase += cb[i];
  int n = cb[b];
  int src = b * CAP;
  for (int i = tid; i < n; i += 1024) atomicAdd(&cnt[buck[src + i].x >> 17], 1);
  __syncthreads();
  sc[i0] = cnt[i0]; sc[i1] = cnt[i1];
  __syncthreads();
  for (int off = 1; off < 2048; off <<= 1) {
    int v0 = (i0 >= off) ? sc[i0 - off] : 0;
    int v1 = (i1 >= off) ? sc[i1 - off] : 0;
    __syncthreads();
    sc[i0] += v0; sc[i1] += v1;
    __syncthreads();
  }
  int r0 = b * 2048;
  int s0 = sc[i0] - cnt[i0], s1 = sc[i1] - cnt[i1];
  if (r0 + i0 < NN) ptr[r0 + i0] = gbase + s0;
  if (r0 + i1 < NN) ptr[r0 + i1] = gbase + s1;
  if (b == 0 && tid == 0) ptr[NN] = NE;
  cnt[i0] = s0; cnt[i1] = s1;
  __syncthreads();
  for (int i = tid; i < n; i += 1024) {
    uint2 e = buck[src + i];
    int rl = e.x >> 17;
    int k = atomicAdd(&cnt[rl], 1);
    cv[gbase + k] = make_uint2(e.x & 0x1FFFFu, e.y);
  }
}

// ---- D3: t = spmm(xb): 32 lanes/row, 16x batch + cv prefetch, nt ---------
__global__ void spmm_x_kernel(const int* __restrict__ ptr, const uint2* __restrict__ cv,
                              const uint2* __restrict__ xb, uint2* __restrict__ t) {
  int r = blockIdx.x * 8 + (threadIdx.x >> 5);
  int k = threadIdx.x & 31;
  int s = ptr[r], e = ptr[r + 1];
  float a0 = 0.f, a1 = 0.f, a2 = 0.f, a3 = 0.f;
  int i = s;
  int nb16 = (e - s) >> 4;             // full 16-batches
  if (nb16 > 0) {
    u32x2 ee[16], en[16];
#pragma unroll
    for (int j = 0; j < 16; ++j) ee[j] = ntl_u2(&cv[i + j]);
    for (int b = 0; b < nb16; ++b) {
      uint2 pp[16];
#pragma unroll
      for (int j = 0; j < 16; ++j) pp[j] = xb[ee[j].x * 32 + k];
      bool more = (b + 1 < nb16);
      if (more) {
#pragma unroll
        for (int j = 0; j < 16; ++j) en[j] = ntl_u2(&cv[i + 16 + j]);
      }
#pragma unroll
      for (int j = 0; j < 16; ++j) {
        float v = __uint_as_float(ee[j].y);
        a0 += v * bflo(pp[j].x); a1 += v * bfhi(pp[j].x);
        a2 += v * bflo(pp[j].y); a3 += v * bfhi(pp[j].y);
      }
      if (more) {
#pragma unroll
        for (int j = 0; j < 16; ++j) ee[j] = en[j];
      }
      i += 16;
    }
  }
  if (i + 8 <= e) {
    u32x2 ee[8]; uint2 pp[8];
#pragma unroll
    for (int j = 0; j < 8; ++j) ee[j] = ntl_u2(&cv[i + j]);
#pragma unroll
    for (int j = 0; j < 8; ++j) pp[j] = xb[ee[j].x * 32 + k];
#pragma unroll
    for (int j = 0; j < 8; ++j) {
      float v = __uint_as_float(ee[j].y);
      a0 += v * bflo(pp[j].x); a1 += v * bfhi(pp[j].x);
      a2 += v * bflo(pp[j].y); a3 += v * bfhi(pp[j].y);
    }
    i += 8;
  }
  if (i + 4 <= e) {
    u32x2 ee[4]; uint2 pp[4];
#pragma unroll
    for (int j = 0; j < 4; ++j) ee[j] = ntl_u2(&cv[i + j]);
#pragma unroll
    for (int j = 0; j < 4; ++j) pp[j] = xb[ee[j].x * 32 + k];
#pragma unroll
    for (int j = 0; j < 4; ++j) {
      float v = __uint_as_float(ee[j].y);
      a0 += v * bflo(pp[j].x); a1 += v * bfhi(pp[j].x);
      a2 += v * bflo(pp[j].y); a3 += v * bfhi(pp[j].y);
    }
    i += 4;
  }
  for (; i < e; ++i) {
    u32x2 ev = ntl_u2(&cv[i]);
    float v = __uint_as_float(ev.y);
    uint2 p = xb[ev.x * 32 + k];
    a0 += v * bflo(p.x); a1 += v * bfhi(p.x);
    a2 += v * bflo(p.y); a3 += v * bfhi(p.y);
  }
  nts_u2(&t[r * 32 + k], pack2(a0, a1), pack2(a2, a3));
}

// ---- D4 pass A (MFMA): U = relu(T@W0); Z^T = Wcat^T @ U^T (masked) -------
#define SWZ(row, byte) ((row) * 256 + ((byte) ^ ((((row) >> 1) & 7) << 4)))
__global__ __launch_bounds__(512, 4) void pass_a_kernel(
    const uint* __restrict__ tb, const ushort* __restrict__ w0t,
    const ushort* __restrict__ wcatT,
    const uint* __restrict__ m1, const uint* __restrict__ m2,
    ushort* __restrict__ zz) {
  __shared__ __align__(16) char ldsb[69632];
  uint* mlds = (uint*)(ldsb + 65536);          // [2][128][4]

  int t = threadIdx.x;
  int r0 = blockIdx.x * 128;
  int wid = t >> 6, l = t & 63, lc = l & 15, lk = l >> 4;

#pragma unroll
  for (int i = 0; i < 4; ++i) {
    int lin = i * 512 + t;            // 0..2047
    int row = lin >> 4, seg = lin & 15;
    int gr = r0 + row;
    uint4 v = make_uint4(0, 0, 0, 0);
    if (gr < NN) v = ((const uint4*)(tb + (size_t)gr * 64))[seg];
    *(uint4*)&ldsb[SWZ(row, seg * 16)] = v;
    uint4 w = ((const uint4*)w0t)[lin];
    *(uint4*)&ldsb[32768 + SWZ(row, seg * 16)] = w;
  }
#pragma unroll
  for (int i = 0; i < 2; ++i) {
    int idx = t;
    int row = idx >> 2, word = idx & 3;
    int gr = r0 + row;
    uint v = 0;
    if (gr < NN) v = (i == 0 ? m1 : m2)[gr * 4 + word];
    mlds[i * 512 + idx] = v;
  }
  __syncthreads();

  short8 af[4];
#pragma unroll
  for (int s = 0; s < 4; ++s) {
    U4S8 tmp; tmp.u = *(uint4*)&ldsb[SWZ(16 * wid + lc, 64 * s + 16 * lk)];
    af[s] = tmp.s;
  }
  f32x4 acc[8];
#pragma unroll
  for (int n = 0; n < 8; ++n) acc[n] = (f32x4)(0.f);
#pragma unroll
  for (int n = 0; n < 8; ++n) {
#pragma unroll
    for (int s = 0; s < 4; ++s) {
      U4S8 tmp; tmp.u = *(uint4*)&ldsb[32768 + SWZ(16 * n + lc, 64 * s + 16 * lk)];
      acc[n] = __builtin_amdgcn_mfma_f32_16x16x32_bf16(af[s], tmp.s, acc[n], 0, 0, 0);
    }
  }
  __syncthreads();

#pragma unroll
  for (int reg = 0; reg < 4; ++reg) {
    int row = 16 * wid + 4 * lk + reg;
    uint4 w1q = *(uint4*)&mlds[row * 4];
    uint4 w2q = *(uint4*)&mlds[512 + row * 4];
    uint w1a[4] = {w1q.x, w1q.y, w1q.z, w1q.w};
    uint w2a[4] = {w2q.x, w2q.y, w2q.z, w2q.w};
#pragma unroll
    for (int n = 0; n < 8; ++n) {
      float v = fmaxf(acc[n][reg], 0.f) * 1.25f;
      ushort ub = (ushort)f2bf(v);
      int bit = (n & 1) * 16 + lc;
      ushort u1 = ((w1a[n >> 1] >> bit) & 1u) ? ub : (ushort)0;
      ushort u2 = ((w2a[n >> 1] >> bit) & 1u) ? ub : (ushort)0;
      int ad = SWZ(row, 32 * n + 2 * lc);
      *(ushort*)&ldsb[ad] = u1;
      *(ushort*)&ldsb[32768 + ad] = u2;
    }
  }
  __syncthreads();

  f32x4 acc2[7];
#pragma unroll
  for (int n = 0; n < 7; ++n) acc2[n] = (f32x4)(0.f);
#pragma unroll
  for (int n2 = 0; n2 < 7; ++n2) {
    int ubase = (n2 < 3) ? 0 : 32768;
#pragma unroll
    for (int s = 0; s < 4; ++s) {
      U4S8 a2; a2.u = ((const uint4*)wcatT)[(16 * n2 + lc) * 16 + 4 * s + lk];
      U4S8 b2; b2.u = *(uint4*)&ldsb[ubase + SWZ(16 * wid + lc, 64 * s + 16 * lk)];
      acc2[n2] = __builtin_amdgcn_mfma_f32_16x16x32_bf16(a2.s, b2.s, acc2[n2], 0, 0, 0);
    }
  }

  int r = r0 + 16 * wid + lc;
  if (r < NN) {
#pragma unroll
    for (int n2 = 0; n2 < 7; ++n2) {
      if (n2 == 2 && lk >= 2) continue;          // W1 pad cols 40..47
      int cb = 16 * n2 + 4 * lk;
      if (n2 >= 3) cb -= 8;
      uint2 v = make_uint2(pack2(acc2[n2][0], acc2[n2][1]),
                           pack2(acc2[n2][2], acc2[n2][3]));
      *(uint2*)(zz + (size_t)r * ZCP + cb) = v;   // padded 256-B rows
    }
  }
}

// ---- D5: out = spmm(z): 32 lanes/row, 16x batch + cv prefetch, nt --------
__global__ void gather_out_kernel(const int* __restrict__ ptr, const uint2* __restrict__ cv,
                                  const uint2* __restrict__ zp, float* __restrict__ out) {
  int r = blockIdx.x * 8 + (threadIdx.x >> 5);
  int k = threadIdx.x & 31;
  if (k >= 26) return;
  int s = ptr[r], e = ptr[r + 1];
  float a0 = 0.f, a1 = 0.f, a2 = 0.f, a3 = 0.f;
  int i = s;
  int nb16 = (e - s) >> 4;
  if (nb16 > 0) {
    u32x2 ee[16], en[16];
#pragma unroll
    for (int j = 0; j < 16; ++j) ee[j] = ntl_u2(&cv[i + j]);
    for (int b = 0; b < nb16; ++b) {
      uint2 pp[16];
#pragma unroll
      for (int j = 0; j < 16; ++j) pp[j] = zp[ee[j].x * 32 + k];
      bool more = (b + 1 < nb16);
      if (more) {
#pragma unroll
        for (int j = 0; j < 16; ++j) en[j] = ntl_u2(&cv[i + 16 + j]);
      }
#pragma unroll
      for (int j = 0; j < 16; ++j) {
        float v = __uint_as_float(ee[j].y);
        a0 += v * bflo(pp[j].x); a1 += v * bfhi(pp[j].x);
        a2 += v * bflo(pp[j].y); a3 += v * bfhi(pp[j].y);
      }
      if (more) {
#pragma unroll
        for (int j = 0; j < 16; ++j) ee[j] = en[j];
      }
      i += 16;
    }
  }
  if (i + 8 <= e) {
    u32x2 ee[8]; uint2 pp[8];
#pragma unroll
    for (int j = 0; j < 8; ++j) ee[j] = ntl_u2(&cv[i + j]);
#pragma unroll
    for (int j = 0; j < 8; ++j) pp[j] = zp[ee[j].x * 32 + k];
#pragma unroll
    for (int j = 0; j < 8; ++j) {
      float v = __uint_as_float(ee[j].y);
      a0 += v * bflo(pp[j].x); a1 += v * bfhi(pp[j].x);
      a2 += v * bflo(pp[j].y); a3 += v * bfhi(pp[j].y);
    }
    i += 8;
  }
  if (i + 4 <= e) {
    u32x2 ee[4]; uint2 pp[4];
#pragma unroll
    for (int j = 0; j < 4; ++j) ee[j] = ntl_u2(&cv[i + j]);
#pragma unroll
    for (int j = 0; j < 4; ++j) pp[j] = zp[ee[j].x * 32 + k];
#pragma unroll
    for (int j = 0; j < 4; ++j) {
      float v = __uint_as_float(ee[j].y);
      a0 += v * bflo(pp[j].x); a1 += v * bfhi(pp[j].x);
      a2 += v * bflo(pp[j].y); a3 += v * bfhi(pp[j].y);
    }
    i += 4;
  }
  for (; i < e; ++i) {
    u32x2 ev = ntl_u2(&cv[i]);
    float v = __uint_as_float(ev.y);
    uint2 p = zp[ev.x * 32 + k];
    a0 += v * bflo(p.x); a1 += v * bfhi(p.x);
    a2 += v * bflo(p.y); a3 += v * bfhi(p.y);
  }
  if (k < 10) {
    nts_f4(out + (size_t)r * DO1 + 4 * k, a0, a1, a2, a3);
  } else {
    nts_f4(out + OUT_S_OFF + (size_t)r * DO2 + 4 * (k - 10), a0, a1, a2, a3);
  }
}

// ---------------- launch ----------------
extern "C" void kernel_launch(void* const* d_in, const int* in_sizes, int n_in,
                              void* d_out, int out_size, void* d_ws, size_t ws_size,
                              hipStream_t stream) {
  const float* x       = (const float*)d_in[0];
  const int*   adj_row = (const int*)d_in[1];
  const int*   adj_col = (const int*)d_in[2];
  const float* adj_val = (const float*)d_in[3];
  const float* W0      = (const float*)d_in[4];
  const float* W1      = (const float*)d_in[5];
  const float* Wss     = (const float*)d_in[6];
  float* out = (float*)d_out;

  char* ws = (char*)d_ws;
  uint*   t_bf  = (uint*)(ws + 0);           // 25,600,000 B bf16 t
  uint2*  buck  = (uint2*)(ws + 0);          // 14,112,000 B (aliases t_bf)
  uint*   xb    = (uint*)(ws + 25600000);    // 25,600,000 B bf16 x
  ushort* zz    = (ushort*)(ws + 25600000);  // 25,600,000 B bf16 z padded (aliases xb)
  uint*   m1    = (uint*)(ws + 51200000);    //  1,600,000 B
  uint*   m2    = (uint*)(ws + 52800000);    //  1,600,000 B
  int*    ptr   = (int*)(ws + 54400000);     //    400,004 B
  ushort* w0t   = (ushort*)(ws + 54800016);  //     32,768 B
  ushort* wcatT = (ushort*)(ws + 54832784);  //     28,672 B
  int*    curs  = (int*)(ws + 54861456);     //        196 B
  uint2*  cv    = (uint2*)(ws + 55600016);   // 12,800,000 B (end 68,400,016)

  hipMemsetAsync(curs, 0, NB * sizeof(int), stream);
  bin_conv_prep_kernel<<<BINB + CONVB + WPREPB, 256, 0, stream>>>(
      adj_row, adj_col, adj_val, curs, buck, x, xb, W0, W1, Wss, w0t, wcatT);
  csr_mask_kernel<<<NB + MASK1K, 1024, 0, stream>>>(buck, curs, ptr, cv, m1, m2);
  spmm_x_kernel<<<12500, 256, 0, stream>>>(ptr, cv, (const uint2*)xb, (uint2*)t_bf);
  pass_a_kernel<<<782, 512, 0, stream>>>(t_bf, w0t, wcatT, m1, m2, zz);
  gather_out_kernel<<<12500, 256, 0, stream>>>(ptr, cv, (const uint2*)zz, out);
}

// Round 19
// 276.736 us; speedup vs baseline: 1.5359x; 1.5359x over previous
//
#include <hip/hip_runtime.h>
#include <stdint.h>

// net_gcn_multitask — MI355X.  (round-16 configuration — best measured)
//   memset: bucket cursors = 0
//   D1 bin_conv_prep: [bin | convx | w0t/wcatT]      (pure memory-bound)
//   D2 csr_mask: [per-bucket CSR (49 CUs) | threefry masks (207 CUs, spatial)]
//   D3 spmm_x: t = spmm(xb)       [32-lane/row gather, 16x unrolled]
//   D4 pass_a: U=relu(t@W0) [MFMA]; z=[drop1(U)@W1 | drop2(U)@Wss], 256B rows
//   D5 gather_out: h|s = spmm(z)  [32-lane/row gather, 16x unrolled]

#define NN 100000
#define NE 1600000
#define D 128
#define NW 400000
#define ZCP 128        // padded z row stride (ushorts) = 256 B
#define DO1 40
#define DO2 64
#define OUT_S_OFF 4000000
#define KEEP_THR 6710886u
#define NB 49
#define CAP 36000
#define BINB 196
#define CONVB 12500
#define WPREPB 120
#define MASK1K 782     // ceil(2*NW / 1024)

typedef unsigned int uint;
typedef __attribute__((ext_vector_type(4))) float f32x4;
typedef __attribute__((ext_vector_type(8))) short short8;
union U4S8 { uint4 u; short8 s; };

// ---------------- bf16 helpers ----------------
__device__ __forceinline__ float bflo(uint p) { return __uint_as_float(p << 16); }
__device__ __forceinline__ float bfhi(uint p) { return __uint_as_float(p & 0xffff0000u); }
__device__ __forceinline__ uint f2bf(float f) {
  uint u = __float_as_uint(f);
  return (u + 0x7fffu + ((u >> 16) & 1u)) >> 16;   // RTNE
}
__device__ __forceinline__ uint pack2(float lo, float hi) {
  return f2bf(lo) | (f2bf(hi) << 16);
}

// ------- threefry2x32 (JAX partitionable; verified) ---------------------
#define ROTL(x, r) __builtin_rotateleft32((x), (r))
__device__ __forceinline__ void tf2x32(uint k0, uint k1, uint x0, uint x1,
                                       uint& o0, uint& o1) {
  uint ks2 = k0 ^ k1 ^ 0x1BD11BDAu;
  x0 += k0; x1 += k1;
#define TFR(r) { x0 += x1; x1 = ROTL(x1, r); x1 ^= x0; }
  TFR(13) TFR(15) TFR(26) TFR(6)
  x0 += k1;  x1 += ks2 + 1u;
  TFR(17) TFR(29) TFR(16) TFR(24)
  x0 += ks2; x1 += k0 + 2u;
  TFR(13) TFR(15) TFR(26) TFR(6)
  x0 += k0;  x1 += k1 + 3u;
  TFR(17) TFR(29) TFR(16) TFR(24)
  x0 += k1;  x1 += ks2 + 4u;
  TFR(13) TFR(15) TFR(26) TFR(6)
  x0 += ks2; x1 += k0 + 5u;
#undef TFR
  o0 = x0; o1 = x1;
}

// ---- D1: [bin | convx | weight transpose], 256 thr (pure memory) ---------
__global__ void bin_conv_prep_kernel(
    const int* __restrict__ row, const int* __restrict__ col,
    const float* __restrict__ val, int* __restrict__ cursor,
    uint2* __restrict__ buck,
    const float* __restrict__ x, uint* __restrict__ xb,
    const float* __restrict__ W0, const float* __restrict__ W1,
    const float* __restrict__ Wss,
    ushort* __restrict__ w0t, ushort* __restrict__ wcatT) {
  int bid = blockIdx.x, tid = threadIdx.x;
  if (bid < BINB) {
    __shared__ int h[NB];
    __shared__ int base[NB];
    if (tid < NB) h[tid] = 0;
    __syncthreads();
    int e0 = bid * 8192;
#pragma unroll 4
    for (int j = 0; j < 32; ++j) {
      int e = e0 + j * 256 + tid;
      if (e < NE) atomicAdd(&h[row[e] >> 11], 1);
    }
    __syncthreads();
    if (tid < NB) {
      int c = h[tid];
      base[tid] = c ? (tid * CAP + atomicAdd(&cursor[tid], c)) : 0;
      h[tid] = 0;
    }
    __syncthreads();
#pragma unroll 4
    for (int j = 0; j < 32; ++j) {
      int e = e0 + j * 256 + tid;
      if (e < NE) {
        int r = row[e];
        int b = r >> 11;
        int k = atomicAdd(&h[b], 1);
        int idx = base[b] + k;
        int lim = (b + 1) * CAP;
        if (idx >= lim) idx = lim - 1;   // overflow guard (never at 18 sigma)
        buck[idx] = make_uint2(((uint)(r & 2047) << 17) | (uint)col[e],
                               __float_as_uint(val[e]));
      }
    }
  } else if (bid < BINB + CONVB) {
    int i = (bid - BINB) * 256 + tid;   // float4 index, 3.2M
    float4 v = ((const float4*)x)[i];
    ((uint2*)xb)[i] = make_uint2(pack2(v.x, v.y), pack2(v.z, v.w));
  } else {
    int idx = (bid - BINB - CONVB) * 256 + tid;   // 0..30719
    if (idx < 16384) {
      int c = idx >> 7, k = idx & 127;
      w0t[idx] = (ushort)f2bf(W0[k * D + c]);
    } else {
      int j = idx - 16384;                         // 0..14335
      int c = j >> 7, k = j & 127;
      float v = (c < 40) ? W1[k * DO1 + c] : ((c < 48) ? 0.f : Wss[k * DO2 + (c - 48)]);
      wcatT[j] = (ushort)f2bf(v);
    }
  }
}

// ---- D2: [csr (49 blocks) | masks (782 blocks, spatial)] 1024 thr --------
__global__ __launch_bounds__(1024) void csr_mask_kernel(
    const uint2* __restrict__ buck, const int* __restrict__ cursor,
    int* __restrict__ ptr, uint2* __restrict__ cv,
    uint* __restrict__ m1, uint* __restrict__ m2) {
  int bid = blockIdx.x, tid = threadIdx.x;
  if (bid >= NB) {
    int t = (bid - NB) * 1024 + tid;
    if (t >= 2 * NW) return;
    uint a0, a1, b0, b1;
    tf2x32(0u, 42u, 0u, 0u, a0, a1);   // child key 0 (const-folded)
    tf2x32(0u, 42u, 0u, 1u, b0, b1);   // child key 1
    bool second = (t >= NW);
    uint w  = second ? (uint)(t - NW) : (uint)t;
    uint k0 = second ? b0 : a0;
    uint k1 = second ? b1 : a1;
    uint base = w * 32u;
    uint word = 0u;
#pragma unroll
    for (int i = 0; i < 32; ++i) {
      uint o0, o1;
      tf2x32(k0, k1, 0u, base + (uint)i, o0, o1);
      word |= (uint)(((o0 ^ o1) >> 9) <= KEEP_THR) << i;
    }
    (second ? m2 : m1)[w] = word;
    return;
  }
  __shared__ int cnt[2048];
  __shared__ int sc[2048];
  __shared__ int cb[NB];
  int b = bid;
  if (tid < NB) cb[tid] = min(cursor[tid], CAP);
  int i0 = tid, i1 = tid + 1024;
  cnt[i0] = 0; cnt[i1] = 0;
  __syncthreads();
  int gbase = 0;
  for (int i = 0; i < b; ++i) gbase += cb[i];
  int n = cb[b];
  int src = b * CAP;
  for (int i = tid; i < n; i += 1024) atomicAdd(&cnt[buck[src + i].x >> 17], 1);
  __syncthreads();
  sc[i0] = cnt[i0]; sc[i1] = cnt[i1];
  __syncthreads();
  for (int off = 1; off < 2048; off <<= 1) {
    int v0 = (i0 >= off) ? sc[i0 - off] : 0;
    int v1 = (i1 >= off) ? sc[i1 - off] : 0;
    __syncthreads();
    sc[i0] += v0; sc[i1] += v1;
    __syncthreads();
  }
  int r0 = b * 2048;
  int s0 = sc[i0] - cnt[i0], s1 = sc[i1] - cnt[i1];
  if (r0 + i0 < NN) ptr[r0 + i0] = gbase + s0;
  if (r0 + i1 < NN) ptr[r0 + i1] = gbase + s1;
  if (b == 0 && tid == 0) ptr[NN] = NE;
  cnt[i0] = s0; cnt[i1] = s1;
  __syncthreads();
  for (int i = tid; i < n; i += 1024) {
    uint2 e = buck[src + i];
    int rl = e.x >> 17;
    int k = atomicAdd(&cnt[rl], 1);
    cv[gbase + k] = make_uint2(e.x & 0x1FFFFu, e.y);
  }
}

// ---- D3: t = spmm(xb): 32 lanes/row, 16x-unrolled edge loop --------------
__global__ void spmm_x_kernel(const int* __restrict__ ptr, const uint2* __restrict__ cv,
                              const uint2* __restrict__ xb, uint2* __restrict__ t) {
  int r = blockIdx.x * 8 + (threadIdx.x >> 5);
  int k = threadIdx.x & 31;
  int s = ptr[r], e = ptr[r + 1];
  float a0 = 0.f, a1 = 0.f, a2 = 0.f, a3 = 0.f;
  int i = s;
  for (; i + 16 <= e; i += 16) {
    uint2 ee[16], pp[16];
#pragma unroll
    for (int j = 0; j < 16; ++j) ee[j] = cv[i + j];
#pragma unroll
    for (int j = 0; j < 16; ++j) pp[j] = xb[ee[j].x * 32 + k];
#pragma unroll
    for (int j = 0; j < 16; ++j) {
      float v = __uint_as_float(ee[j].y);
      a0 += v * bflo(pp[j].x); a1 += v * bfhi(pp[j].x);
      a2 += v * bflo(pp[j].y); a3 += v * bfhi(pp[j].y);
    }
  }
  if (i + 8 <= e) {
    uint2 ee[8], pp[8];
#pragma unroll
    for (int j = 0; j < 8; ++j) ee[j] = cv[i + j];
#pragma unroll
    for (int j = 0; j < 8; ++j) pp[j] = xb[ee[j].x * 32 + k];
#pragma unroll
    for (int j = 0; j < 8; ++j) {
      float v = __uint_as_float(ee[j].y);
      a0 += v * bflo(pp[j].x); a1 += v * bfhi(pp[j].x);
      a2 += v * bflo(pp[j].y); a3 += v * bfhi(pp[j].y);
    }
    i += 8;
  }
  if (i + 4 <= e) {
    uint2 ee[4], pp[4];
#pragma unroll
    for (int j = 0; j < 4; ++j) ee[j] = cv[i + j];
#pragma unroll
    for (int j = 0; j < 4; ++j) pp[j] = xb[ee[j].x * 32 + k];
#pragma unroll
    for (int j = 0; j < 4; ++j) {
      float v = __uint_as_float(ee[j].y);
      a0 += v * bflo(pp[j].x); a1 += v * bfhi(pp[j].x);
      a2 += v * bflo(pp[j].y); a3 += v * bfhi(pp[j].y);
    }
    i += 4;
  }
  for (; i < e; ++i) {
    uint2 ev = cv[i];
    float v = __uint_as_float(ev.y);
    uint2 p = xb[ev.x * 32 + k];
    a0 += v * bflo(p.x); a1 += v * bfhi(p.x);
    a2 += v * bflo(p.y); a3 += v * bfhi(p.y);
  }
  t[r * 32 + k] = make_uint2(pack2(a0, a1), pack2(a2, a3));
}

// ---- D4 pass A (MFMA): U = relu(T@W0); Z^T = Wcat^T @ U^T (masked) -------
#define SWZ(row, byte) ((row) * 256 + ((byte) ^ ((((row) >> 1) & 7) << 4)))
__global__ __launch_bounds__(512, 4) void pass_a_kernel(
    const uint* __restrict__ tb, const ushort* __restrict__ w0t,
    const ushort* __restrict__ wcatT,
    const uint* __restrict__ m1, const uint* __restrict__ m2,
    ushort* __restrict__ zz) {
  __shared__ __align__(16) char ldsb[69632];
  uint* mlds = (uint*)(ldsb + 65536);          // [2][128][4]

  int t = threadIdx.x;
  int r0 = blockIdx.x * 128;
  int wid = t >> 6, l = t & 63, lc = l & 15, lk = l >> 4;

#pragma unroll
  for (int i = 0; i < 4; ++i) {
    int lin = i * 512 + t;            // 0..2047
    int row = lin >> 4, seg = lin & 15;
    int gr = r0 + row;
    uint4 v = make_uint4(0, 0, 0, 0);
    if (gr < NN) v = ((const uint4*)(tb + (size_t)gr * 64))[seg];
    *(uint4*)&ldsb[SWZ(row, seg * 16)] = v;
    uint4 w = ((const uint4*)w0t)[lin];
    *(uint4*)&ldsb[32768 + SWZ(row, seg * 16)] = w;
  }
#pragma unroll
  for (int i = 0; i < 2; ++i) {
    int idx = t;
    int row = idx >> 2, word = idx & 3;
    int gr = r0 + row;
    uint v = 0;
    if (gr < NN) v = (i == 0 ? m1 : m2)[gr * 4 + word];
    mlds[i * 512 + idx] = v;
  }
  __syncthreads();

  short8 af[4];
#pragma unroll
  for (int s = 0; s < 4; ++s) {
    U4S8 tmp; tmp.u = *(uint4*)&ldsb[SWZ(16 * wid + lc, 64 * s + 16 * lk)];
    af[s] = tmp.s;
  }
  f32x4 acc[8];
#pragma unroll
  for (int n = 0; n < 8; ++n) acc[n] = (f32x4)(0.f);
#pragma unroll
  for (int n = 0; n < 8; ++n) {
#pragma unroll
    for (int s = 0; s < 4; ++s) {
      U4S8 tmp; tmp.u = *(uint4*)&ldsb[32768 + SWZ(16 * n + lc, 64 * s + 16 * lk)];
      acc[n] = __builtin_amdgcn_mfma_f32_16x16x32_bf16(af[s], tmp.s, acc[n], 0, 0, 0);
    }
  }
  __syncthreads();

#pragma unroll
  for (int reg = 0; reg < 4; ++reg) {
    int row = 16 * wid + 4 * lk + reg;
    uint4 w1q = *(uint4*)&mlds[row * 4];
    uint4 w2q = *(uint4*)&mlds[512 + row * 4];
    uint w1a[4] = {w1q.x, w1q.y, w1q.z, w1q.w};
    uint w2a[4] = {w2q.x, w2q.y, w2q.z, w2q.w};
#pragma unroll
    for (int n = 0; n < 8; ++n) {
      float v = fmaxf(acc[n][reg], 0.f) * 1.25f;
      ushort ub = (ushort)f2bf(v);
      int bit = (n & 1) * 16 + lc;
      ushort u1 = ((w1a[n >> 1] >> bit) & 1u) ? ub : (ushort)0;
      ushort u2 = ((w2a[n >> 1] >> bit) & 1u) ? ub : (ushort)0;
      int ad = SWZ(row, 32 * n + 2 * lc);
      *(ushort*)&ldsb[ad] = u1;
      *(ushort*)&ldsb[32768 + ad] = u2;
    }
  }
  __syncthreads();

  f32x4 acc2[7];
#pragma unroll
  for (int n = 0; n < 7; ++n) acc2[n] = (f32x4)(0.f);
#pragma unroll
  for (int n2 = 0; n2 < 7; ++n2) {
    int ubase = (n2 < 3) ? 0 : 32768;
#pragma unroll
    for (int s = 0; s < 4; ++s) {
      U4S8 a2; a2.u = ((const uint4*)wcatT)[(16 * n2 + lc) * 16 + 4 * s + lk];
      U4S8 b2; b2.u = *(uint4*)&ldsb[ubase + SWZ(16 * wid + lc, 64 * s + 16 * lk)];
      acc2[n2] = __builtin_amdgcn_mfma_f32_16x16x32_bf16(a2.s, b2.s, acc2[n2], 0, 0, 0);
    }
  }

  int r = r0 + 16 * wid + lc;
  if (r < NN) {
#pragma unroll
    for (int n2 = 0; n2 < 7; ++n2) {
      if (n2 == 2 && lk >= 2) continue;          // W1 pad cols 40..47
      int cb = 16 * n2 + 4 * lk;
      if (n2 >= 3) cb -= 8;
      uint2 v = make_uint2(pack2(acc2[n2][0], acc2[n2][1]),
                           pack2(acc2[n2][2], acc2[n2][3]));
      *(uint2*)(zz + (size_t)r * ZCP + cb) = v;   // padded 256-B rows
    }
  }
}

// ---- D5: out = spmm(z): 32 lanes/row (26 active), 16x unrolled -----------
__global__ void gather_out_kernel(const int* __restrict__ ptr, const uint2* __restrict__ cv,
                                  const uint2* __restrict__ zp, float* __restrict__ out) {
  int r = blockIdx.x * 8 + (threadIdx.x >> 5);
  int k = threadIdx.x & 31;
  if (k >= 26) return;
  int s = ptr[r], e = ptr[r + 1];
  float a0 = 0.f, a1 = 0.f, a2 = 0.f, a3 = 0.f;
  int i = s;
  for (; i + 16 <= e; i += 16) {
    uint2 ee[16], pp[16];
#pragma unroll
    for (int j = 0; j < 16; ++j) ee[j] = cv[i + j];
#pragma unroll
    for (int j = 0; j < 16; ++j) pp[j] = zp[ee[j].x * 32 + k];
#pragma unroll
    for (int j = 0; j < 16; ++j) {
      float v = __uint_as_float(ee[j].y);
      a0 += v * bflo(pp[j].x); a1 += v * bfhi(pp[j].x);
      a2 += v * bflo(pp[j].y); a3 += v * bfhi(pp[j].y);
    }
  }
  if (i + 8 <= e) {
    uint2 ee[8], pp[8];
#pragma unroll
    for (int j = 0; j < 8; ++j) ee[j] = cv[i + j];
#pragma unroll
    for (int j = 0; j < 8; ++j) pp[j] = zp[ee[j].x * 32 + k];
#pragma unroll
    for (int j = 0; j < 8; ++j) {
      float v = __uint_as_float(ee[j].y);
      a0 += v * bflo(pp[j].x); a1 += v * bfhi(pp[j].x);
      a2 += v * bflo(pp[j].y); a3 += v * bfhi(pp[j].y);
    }
    i += 8;
  }
  if (i + 4 <= e) {
    uint2 ee[4], pp[4];
#pragma unroll
    for (int j = 0; j < 4; ++j) ee[j] = cv[i + j];
#pragma unroll
    for (int j = 0; j < 4; ++j) pp[j] = zp[ee[j].x * 32 + k];
#pragma unroll
    for (int j = 0; j < 4; ++j) {
      float v = __uint_as_float(ee[j].y);
      a0 += v * bflo(pp[j].x); a1 += v * bfhi(pp[j].x);
      a2 += v * bflo(pp[j].y); a3 += v * bfhi(pp[j].y);
    }
    i += 4;
  }
  for (; i < e; ++i) {
    uint2 ev = cv[i];
    float v = __uint_as_float(ev.y);
    uint2 p = zp[ev.x * 32 + k];
    a0 += v * bflo(p.x); a1 += v * bfhi(p.x);
    a2 += v * bflo(p.y); a3 += v * bfhi(p.y);
  }
  if (k < 10) {
    *(float4*)(out + (size_t)r * DO1 + 4 * k) = make_float4(a0, a1, a2, a3);
  } else {
    *(float4*)(out + OUT_S_OFF + (size_t)r * DO2 + 4 * (k - 10)) = make_float4(a0, a1, a2, a3);
  }
}

// ---------------- launch ----------------
extern "C" void kernel_launch(void* const* d_in, const int* in_sizes, int n_in,
                              void* d_out, int out_size, void* d_ws, size_t ws_size,
                              hipStream_t stream) {
  const float* x       = (const float*)d_in[0];
  const int*   adj_row = (const int*)d_in[1];
  const int*   adj_col = (const int*)d_in[2];
  const float* adj_val = (const float*)d_in[3];
  const float* W0      = (const float*)d_in[4];
  const float* W1      = (const float*)d_in[5];
  const float* Wss     = (const float*)d_in[6];
  float* out = (float*)d_out;

  char* ws = (char*)d_ws;
  uint*   t_bf  = (uint*)(ws + 0);           // 25,600,000 B bf16 t
  uint2*  buck  = (uint2*)(ws + 0);          // 14,112,000 B (aliases t_bf)
  uint*   xb    = (uint*)(ws + 25600000);    // 25,600,000 B bf16 x
  ushort* zz    = (ushort*)(ws + 25600000);  // 25,600,000 B bf16 z padded (aliases xb)
  uint*   m1    = (uint*)(ws + 51200000);    //  1,600,000 B
  uint*   m2    = (uint*)(ws + 52800000);    //  1,600,000 B
  int*    ptr   = (int*)(ws + 54400000);     //    400,004 B
  ushort* w0t   = (ushort*)(ws + 54800016);  //     32,768 B
  ushort* wcatT = (ushort*)(ws + 54832784);  //     28,672 B
  int*    curs  = (int*)(ws + 54861456);     //        196 B
  uint2*  cv    = (uint2*)(ws + 55600016);   // 12,800,000 B (end 68,400,016)

  hipMemsetAsync(curs, 0, NB * sizeof(int), stream);
  bin_conv_prep_kernel<<<BINB + CONVB + WPREPB, 256, 0, stream>>>(
      adj_row, adj_col, adj_val, curs, buck, x, xb, W0, W1, Wss, w0t, wcatT);
  csr_mask_kernel<<<NB + MASK1K, 1024, 0, stream>>>(buck, curs, ptr, cv, m1, m2);
  spmm_x_kernel<<<12500, 256, 0, stream>>>(ptr, cv, (const uint2*)xb, (uint2*)t_bf);
  pass_a_kernel<<<782, 512, 0, stream>>>(t_bf, w0t, wcatT, m1, m2, zz);
  gather_out_kernel<<<12500, 256, 0, stream>>>(ptr, cv, (const uint2*)zz, out);
}